// Round 14
// baseline (127.010 us; speedup 1.0000x reference)
//
#include <hip/hip_runtime.h>

typedef _Float16 f16;
typedef _Float16 f16x8 __attribute__((ext_vector_type(8)));
typedef _Float16 f16x4 __attribute__((ext_vector_type(4)));
typedef float f32x4 __attribute__((ext_vector_type(4)));

#define MFMA16(a,b,c) __builtin_amdgcn_mfma_f32_16x16x32_f16((a),(b),(c),0,0,0)

__device__ __forceinline__ float sigm(float x){ return 1.0f/(1.0f+__expf(-x)); }
__device__ __forceinline__ float tanhf_(float x){ return 1.0f - 2.0f/(1.0f+__expf(2.0f*x)); }

typedef __attribute__((address_space(1))) unsigned g_u32;
typedef __attribute__((address_space(3))) unsigned l_u32;
__device__ __forceinline__ void gload16(const void* g, void* l){
    __builtin_amdgcn_global_load_lds((g_u32*)g, (l_u32*)l, 16, 0, 0);
}

#define S136 136
#define S68  68
#define S72  72

// d_ws: 0: W12s[384]f32 | 2048: Ws f16 image [128][68] | 20480: Wt f16 image
__global__ __launch_bounds__(256) void k_setup(const float* __restrict__ W1,
                                               const float* __restrict__ b1,
                                               const float* __restrict__ W2,
                                               const float* __restrict__ Ws,
                                               const float* __restrict__ Wt,
                                               void* ws){
    if (blockIdx.x < 16){
        f16* wsi = (f16*)((char*)ws + 2048);
        f16* wti = (f16*)((char*)ws + 20480);
        for (int e = blockIdx.x*256 + threadIdx.x; e < 8704; e += 4096){
            int aux = e/68, n2 = e - 68*aux;
            wsi[e] = (n2<64)? (f16)Ws[n2*128+aux] : (f16)0;
            wti[e] = (n2<64)? (f16)Wt[n2*128+aux] : (f16)0;
        }
    } else {
        int i = threadIdx.x + (blockIdx.x-16)*256;
        if (i < 384){
            int m = i>>6, k = i&63;
            float s = 0.f;
            if (m<5){ for (int c=0;c<128;++c) s += W1[m*128+c]*W2[c*64+k]; }
            else    { for (int c=0;c<128;++c) s += b1[c]*W2[c*64+k]; }
            ((float*)ws)[i] = s;
        }
    }
}

// One block (1024 thr, 16 waves) per batch; 2 blocks/CU -> up to 32 waves/CU.
// Wave-pair wp=w>>1 owns rows [16wp,16wp+16); the two waves split the ct-range
// (ch=w&1). Numerics = R8: Ac=A-2 f16; Y,d2 hi+lo f16; exact fp32 rank-1 paths.
// LDS (81408 B): 0 Alds[128][136] (RES[128][72] overlays after M2)
// | 34816 YH[64][136] -> d2hi -> WsB[128][68] | 52224 YL -> d2lo -> WtB
// | 69632 node_l[640] (t1l/t2l at head) | 72192 W12s[384] | 73728 Wsnd[640]
// | 76288 Wtnd[640] | 78848 sumY | 79104 rsL | 79616 c_ac | 79872 cw
// | 80384 ctw | 80896 g_ac
__global__ __launch_bounds__(1024,8) void k_main(
    const float* __restrict__ adj,  const float* __restrict__ node_g,
    const float* __restrict__ b2,
    const float* __restrict__ Ws,  const float* __restrict__ bs,
    const float* __restrict__ Wt,  const float* __restrict__ bt,
    const float* __restrict__ Wl1, const float* __restrict__ bl1,
    const float* __restrict__ Wl2, const float* __restrict__ bl2,
    const float* __restrict__ Wo,  const float* __restrict__ bo,
    const void* __restrict__ ws,
    float* __restrict__ out)
{
    __shared__ __align__(16) char smem[81408];
    f16*   Alds  = (f16*)(smem);
    f16*   resid = (f16*)(smem);
    f16*   YH    = (f16*)(smem+34816);
    f16*   d2hi  = (f16*)(smem+34816);
    f16*   WsB   = (f16*)(smem+34816);
    f16*   YL    = (f16*)(smem+52224);
    f16*   d2lo  = (f16*)(smem+52224);
    f16*   WtB   = (f16*)(smem+52224);
    float* node_l= (float*)(smem+69632);
    float* t1l   = (float*)(smem+69632);
    float* t2l   = (float*)(smem+70144);
    float* W12s  = (float*)(smem+72192);
    float* Wsnd  = (float*)(smem+73728);
    float* Wtnd  = (float*)(smem+76288);
    float* sumY  = (float*)(smem+78848);
    float* rsL   = (float*)(smem+79104);
    float* c_ac  = (float*)(smem+79616);
    float* cw    = (float*)(smem+79872);
    float* ctw   = (float*)(smem+80384);
    float* g_ac  = (float*)(smem+80896);

    const int bidx = blockIdx.x;
    const int tid  = threadIdx.x;
    const int w    = tid>>6, lane = tid&63;
    const int l15  = lane&15, l4 = lane>>4;
    const int wp   = w>>1, ch = w&1;      // wave-pair, ct-half
    const int rb   = 16*wp + l4*4;        // C/D row base (pair tile)
    const int ir   = 16*wp + l15;         // A-operand row (pair tile)

    // ---- phase 0: zeros + small staging ----
    if (tid<64)  { sumY[tid]=0.f; c_ac[tid]=0.f; }
    if (tid<128) g_ac[tid]=0.f;
    if (tid<640){
        node_l[tid] = node_g[bidx*640+tid];
        Wsnd[tid]   = Ws[8192+tid];
        Wtnd[tid]   = Wt[8192+tid];
    }
    if (tid<384) W12s[tid] = ((const float*)ws)[tid];
    __syncthreads();                                           // B1

    // ---- stream adj (thread owns 16 cells of one row) + Y-build, one phase ----
    {   // stream: row i = tid>>3, cells j0..j0+15, 4 groups of 5 float4
        const int i  = tid>>3;
        const int j0 = (tid&7)*16;
        const float* af = adj + (long long)bidx*81920 + (long long)i*640 + (long long)j0*5;
        float rs_part = 0.f;
        #pragma unroll
        for (int g=0; g<4; ++g){
            const float4* p = (const float4*)(af + g*20);
            float4 v0=p[0], v1=p[1], v2=p[2], v3=p[3], v4=p[4];
            float s0 = v0.y + v0.z + v0.w + v1.x;
            float s1 = v1.z + v1.w + v2.x + v2.y;
            float s2 = v2.w + v3.x + v3.y + v3.z;
            float s3 = v4.x + v4.y + v4.z + v4.w;
            f16x4 o; o[0]=(f16)(s0-2.f); o[1]=(f16)(s1-2.f);
                     o[2]=(f16)(s2-2.f); o[3]=(f16)(s3-2.f);
            *(f16x4*)&Alds[i*S136 + j0 + g*4] = o;
            rs_part += (s0+s1)+(s2+s3);
        }
        rs_part += __shfl_xor(rs_part,1,64);
        rs_part += __shfl_xor(rs_part,2,64);
        rs_part += __shfl_xor(rs_part,4,64);
        if ((tid&7)==0) rsL[i] = rs_part;       // exact fp32 rowsum
    }
    {   // Y = node@W12 + b12 -> split f16 hi+lo; k owned by one 16-lane group
        int k = tid>>4, sub = tid&15, n0 = sub*8;
        float w12v[5];
        #pragma unroll
        for (int m=0;m<5;++m) w12v[m] = W12s[m*64+k];
        float bv = W12s[320+k];
        float sy = 0.f;
        #pragma unroll
        for (int g=0; g<2; ++g){
            f16x4 ph, pl;
            #pragma unroll
            for (int r=0;r<4;++r){
                int n = n0 + g*4 + r;
                float y = bv;
                #pragma unroll
                for (int m=0;m<5;++m) y += node_l[n*5+m]*w12v[m];
                f16 yh = (f16)y;
                f16 yl = (f16)(y - (float)yh);
                ph[r]=yh; pl[r]=yl;
                sy += (float)yh + (float)yl;
            }
            *(f16x4*)&YH[k*S136 + n0 + g*4] = ph;
            *(f16x4*)&YL[k*S136 + n0 + g*4] = pl;
        }
        sy += __shfl_xor(sy,1,64); sy += __shfl_xor(sy,2,64);
        sy += __shfl_xor(sy,4,64); sy += __shfl_xor(sy,8,64);
        if ((tid&15)==0) sumY[k] = sy;          // sole owner: plain store
    }
    __syncthreads();                                           // B2

    // ---- M1: Z = Ac@(YH+YL) + 2*sumY + Y + b2  (2 ct per wave) ----
    f32x4 accZ[2];
    #pragma unroll
    for (int c2=0;c2<2;++c2){
        int k = (2*ch+c2)*16 + l15;
        float base = 2.0f*sumY[k] + b2[k];
        f16x4 yh = *(const f16x4*)&YH[k*S136 + rb];
        f16x4 yl = *(const f16x4*)&YL[k*S136 + rb];
        #pragma unroll
        for (int r=0;r<4;++r) accZ[c2][r] = base + (float)yh[r] + (float)yl[r];
    }
    #pragma unroll
    for (int kk=0;kk<4;++kk){
        int ko = kk*32 + l4*8;
        f16x8 af = *(const f16x8*)&Alds[ir*S136 + ko];
        #pragma unroll
        for (int c2=0;c2<2;++c2){
            int k = (2*ch+c2)*16 + l15;
            f16x8 bh = *(const f16x8*)&YH[k*S136 + ko];
            accZ[c2] = MFMA16(af, bh, accZ[c2]);
            f16x8 bl = *(const f16x8*)&YL[k*S136 + ko];
            accZ[c2] = MFMA16(af, bl, accZ[c2]);
        }
    }
    #pragma unroll
    for (int c2=0;c2<2;++c2){            // column sums of Z
        float v = accZ[c2][0]+accZ[c2][1]+accZ[c2][2]+accZ[c2][3];
        v += __shfl_xor(v,16,64); v += __shfl_xor(v,32,64);
        if (lane<16) atomicAdd(&c_ac[(2*ch+c2)*16+lane], v);
    }
    __syncthreads();                                           // B3

    // ---- d2 = Z - c (split f16, [n2][j]); cw/ctw = (c/128)@Ws/Wt fp32 ----
    #pragma unroll
    for (int c2=0;c2<2;++c2){
        int n2 = (2*ch+c2)*16 + l15; float cv = c_ac[n2]*(1.0f/128.0f);
        f16x4 ph, pl;
        #pragma unroll
        for (int r=0;r<4;++r){
            float d = accZ[c2][r]-cv;
            f16 dh = (f16)d;
            ph[r]=dh; pl[r]=(f16)(d-(float)dh);
        }
        *(f16x4*)&d2hi[n2*S136 + rb] = ph;
        *(f16x4*)&d2lo[n2*S136 + rb] = pl;
    }
    if (tid<256){
        int aux = tid&127;
        const float* Wx = (tid<128)? Ws : Wt;
        float s=0.f;
        #pragma unroll
        for (int n2=0;n2<64;++n2) s += c_ac[n2]*Wx[n2*128+aux];
        ((tid<128)? cw : ctw)[aux] = s*(1.0f/128.0f);
    }
    __syncthreads();                                           // B4

    // ---- M2: acc3 = Ac@(d2hi+d2lo) + d2 ----
    f32x4 acc3[2];
    #pragma unroll
    for (int c2=0;c2<2;++c2){
        int n2 = (2*ch+c2)*16 + l15;
        f16x4 dh = *(const f16x4*)&d2hi[n2*S136 + rb];
        f16x4 dl = *(const f16x4*)&d2lo[n2*S136 + rb];
        #pragma unroll
        for (int r=0;r<4;++r) acc3[c2][r] = (float)dh[r] + (float)dl[r];
    }
    #pragma unroll
    for (int kk=0;kk<4;++kk){
        int ko = kk*32 + l4*8;
        f16x8 af = *(const f16x8*)&Alds[ir*S136 + ko];
        #pragma unroll
        for (int c2=0;c2<2;++c2){
            int n2 = (2*ch+c2)*16 + l15;
            f16x8 bh = *(const f16x8*)&d2hi[n2*S136 + ko];
            acc3[c2] = MFMA16(af, bh, acc3[c2]);
            f16x8 bl = *(const f16x8*)&d2lo[n2*S136 + ko];
            acc3[c2] = MFMA16(af, bl, acc3[c2]);
        }
    }
    __syncthreads();                                           // B5 (Alds+d2 dead)

    // ---- resid (overlays Alds) + DMA Ws/Wt f16 images (over YH/YL) ----
    {
        const uint4* wsg = (const uint4*)((const char*)ws + 2048);
        const uint4* wtg = (const uint4*)((const char*)ws + 20480);
        uint4* wsl = (uint4*)WsB;
        uint4* wtl = (uint4*)WtB;
        gload16(wsg + tid, wsl + (w<<6));
        gload16(wtg + tid, wtl + (w<<6));
        if (w==0){
            gload16(wsg + 1024 + lane, wsl + 1024);
            gload16(wtg + 1024 + lane, wtl + 1024);
        }
    }
    #pragma unroll
    for (int c2=0;c2<2;++c2){
        int n2 = (2*ch+c2)*16 + l15;
        #pragma unroll
        for (int r=0;r<4;++r) resid[(rb+r)*S72 + n2] = (f16)acc3[c2][r];
    }
    __syncthreads();                                           // B6 (drains DMA)

    // ---- G4: S/T = resid@Ws/Wt + (rs+1)*cw/ctw + node-part + bias (4 ct/wave) ----
    {
        float nodev[4][5]; float rs1[4];
        #pragma unroll
        for (int r=0;r<4;++r){
            rs1[r] = rsL[rb+r] + 1.0f;
            #pragma unroll
            for (int m=0;m<5;++m) nodev[r][m] = node_l[(rb+r)*5+m];
        }
        f32x4 aS[4], aT[4];
        #pragma unroll
        for (int ct=0;ct<4;++ct){
            int aux = (4*ch+ct)*16+l15;
            float cwv = cw[aux], ctv = ctw[aux];
            float bsv = bs[aux], btv = bt[aux];
            #pragma unroll
            for (int r=0;r<4;++r){
                float ns=0.f, nt=0.f;
                #pragma unroll
                for (int m=0;m<5;++m){
                    float nv = nodev[r][m];
                    ns += nv*Wsnd[m*128+aux];
                    nt += nv*Wtnd[m*128+aux];
                }
                aS[ct][r] = bsv + rs1[r]*cwv + ns;
                aT[ct][r] = btv + rs1[r]*ctv + nt;
            }
        }
        #pragma unroll
        for (int kk=0;kk<2;++kk){
            int ko = kk*32 + l4*8;
            f16x8 af = *(const f16x8*)&resid[ir*S72 + ko];
            #pragma unroll
            for (int ct=0;ct<4;++ct){
                int aux = (4*ch+ct)*16+l15;
                f16x8 bsf = *(const f16x8*)&WsB[aux*S68 + ko];
                aS[ct] = MFMA16(af, bsf, aS[ct]);
                f16x8 btf = *(const f16x8*)&WtB[aux*S68 + ko];
                aT[ct] = MFMA16(af, btf, aT[ct]);
            }
        }
        #pragma unroll
        for (int ct=0;ct<4;++ct){
            float v = 0.f;
            #pragma unroll
            for (int r=0;r<4;++r) v += sigm(aS[ct][r])*tanhf_(aT[ct][r]);
            v += __shfl_xor(v,16,64); v += __shfl_xor(v,32,64);
            if (lane<16) atomicAdd(&g_ac[(4*ch+ct)*16+lane], v);
        }
    }
    __syncthreads();                                           // B7

    // ---- head (t1l/t2l overlay node_l) ----
    if (tid<128) g_ac[tid] = tanhf_(g_ac[tid]);
    __syncthreads();                                           // B8
    if (tid<512){
        int o = tid>>2, q = tid&3;
        float s = (q==0)? bl1[o] : 0.f;
        #pragma unroll
        for (int a2=0; a2<32; ++a2) s += g_ac[q*32+a2]*Wl1[(q*32+a2)*128+o];
        s += __shfl_xor(s,1,64); s += __shfl_xor(s,2,64);
        if (q==0) t1l[o] = s;
    }
    __syncthreads();                                           // B9
    if (tid<512){
        int o = tid>>3, e = tid&7;
        float s = (e==0)? bl2[o] : 0.f;
        #pragma unroll
        for (int k=0; k<16; ++k) s += t1l[e*16+k]*Wl2[(e*16+k)*64+o];
        s += __shfl_xor(s,1,64); s += __shfl_xor(s,2,64); s += __shfl_xor(s,4,64);
        if (e==0){ t2l[o] = s; out[512 + bidx*64 + o] = s; }   // output 1: g [B,64]
    }
    __syncthreads();                                           // B10
    if (w==0){
        float v = t2l[lane]*Wo[lane];
        v += __shfl_xor(v,1,64);  v += __shfl_xor(v,2,64);
        v += __shfl_xor(v,4,64);  v += __shfl_xor(v,8,64);
        v += __shfl_xor(v,16,64); v += __shfl_xor(v,32,64);
        if (lane==0) out[bidx] = v + bo[0];                    // output 0: out [B,1]
    }
}

extern "C" void kernel_launch(void* const* d_in, const int* in_sizes, int n_in,
                              void* d_out, int out_size, void* d_ws, size_t ws_size,
                              hipStream_t stream) {
    (void)in_sizes; (void)n_in; (void)out_size; (void)ws_size;
    const float* adj  = (const float*)d_in[0];
    const float* node = (const float*)d_in[1];
    const float* W1   = (const float*)d_in[2];
    const float* b1   = (const float*)d_in[3];
    const float* W2   = (const float*)d_in[4];
    const float* b2   = (const float*)d_in[5];
    const float* Ws   = (const float*)d_in[6];
    const float* bs   = (const float*)d_in[7];
    const float* Wt   = (const float*)d_in[8];
    const float* bt   = (const float*)d_in[9];
    const float* Wl1  = (const float*)d_in[10];
    const float* bl1  = (const float*)d_in[11];
    const float* Wl2  = (const float*)d_in[12];
    const float* bl2  = (const float*)d_in[13];
    const float* Wo   = (const float*)d_in[14];
    const float* bo   = (const float*)d_in[15];

    k_setup<<<dim3(18), dim3(256), 0, stream>>>(W1, b1, W2, Ws, Wt, d_ws);
    k_main<<<dim3(512), dim3(1024), 0, stream>>>(adj, node, b2, Ws,bs, Wt,bt,
                                                 Wl1,bl1, Wl2,bl2, Wo,bo,
                                                 d_ws, (float*)d_out);
}